// Round 4
// baseline (366.170 us; speedup 1.0000x reference)
//
#include <hip/hip_runtime.h>
#include <hip/hip_bf16.h>
#include <math.h>

#define BD 2
#define HD 16
#define NSEQ 8192
#define DDIM 64
#define NPROJ 7
#define KBLK 256
#define NSAMP 256
#define NBH (BD*HD)           // 32
#define NB (NSEQ/KBLK)        // 32

#define LOG2E_8 0.18033688011112042f   // log2(e)/8

typedef short bf16x8 __attribute__((ext_vector_type(8)));
typedef float f32x4 __attribute__((ext_vector_type(4)));

// pack two f32 -> u32 of 2 bf16 (RTNE via v_cvt_pk_bf16_f32)
__device__ __forceinline__ unsigned int pk2bf(float a, float b) {
    union { __hip_bfloat162 h; unsigned int u; } t;
    t.h = __float22bfloat162_rn(make_float2(a, b));
    return t.u;
}

// ---------------------------------------------------------------------------
// Kernel A (fused prelude): q-hash + k-dots + k-norm + per-bh max-norm.
// Dot/norm accumulation expressions kept IDENTICAL to the passing kernel
// (hash sign bits are exact-match-critical).
// ---------------------------------------------------------------------------
__global__ __launch_bounds__(256) void prelude_kernel(const float* __restrict__ q,
                                                      const float* __restrict__ k,
                                                      const float* __restrict__ pd,
                                                      float* __restrict__ kdots,
                                                      unsigned int* __restrict__ kmax_bits,
                                                      unsigned char* __restrict__ qh) {
    __shared__ float pds[(DDIM+1)*NPROJ];
    __shared__ float red[256];
    const int tid = threadIdx.x;
    for (int i = tid; i < (DDIM+1)*NPROJ; i += 256) pds[i] = pd[i];
    __syncthreads();

    const int lin = blockIdx.x * 256 + tid;
    const int bh = lin >> 13;

    float acc[NPROJ];
    float4 xv[16];

    // ---- query hash (identical code path to passing version) ----
    {
        const float4* xp = (const float4*)(q + (size_t)lin * DDIM);
        #pragma unroll
        for (int j = 0; j < 16; ++j) xv[j] = xp[j];
        #pragma unroll
        for (int r = 0; r < NPROJ; ++r) acc[r] = 0.f;
        #pragma unroll
        for (int j = 0; j < 16; ++j) {
            float xs[4] = {xv[j].x, xv[j].y, xv[j].z, xv[j].w};
            #pragma unroll
            for (int c = 0; c < 4; ++c) {
                const int d = j*4 + c;
                #pragma unroll
                for (int r = 0; r < NPROJ; ++r) acc[r] += xs[c] * pds[d*NPROJ + r];
            }
        }
        int bin = 0;
        #pragma unroll
        for (int r = 0; r < NPROJ; ++r) bin |= (acc[r] > 0.f) << r;
        qh[lin] = (unsigned char)(bin ^ (bin >> 1));
    }

    // ---- key dots + norm ----
    float nr;
    {
        const float4* xp = (const float4*)(k + (size_t)lin * DDIM);
        #pragma unroll
        for (int j = 0; j < 16; ++j) xv[j] = xp[j];
        #pragma unroll
        for (int r = 0; r < NPROJ; ++r) acc[r] = 0.f;
        #pragma unroll
        for (int j = 0; j < 16; ++j) {
            float xs[4] = {xv[j].x, xv[j].y, xv[j].z, xv[j].w};
            #pragma unroll
            for (int c = 0; c < 4; ++c) {
                const int d = j*4 + c;
                #pragma unroll
                for (int r = 0; r < NPROJ; ++r) acc[r] += xs[c] * pds[d*NPROJ + r];
            }
        }
        float ss = 0.f;
        #pragma unroll
        for (int j = 0; j < 16; ++j) {
            float4 t = xv[j];
            ss += t.x*t.x + t.y*t.y + t.z*t.z + t.w*t.w;
        }
        nr = sqrtf(ss);
        float4* kd = (float4*)(kdots + (size_t)lin * 8);
        kd[0] = make_float4(acc[0], acc[1], acc[2], acc[3]);
        kd[1] = make_float4(acc[4], acc[5], acc[6], nr);
    }

    red[tid] = nr;
    __syncthreads();
    for (int s = 128; s > 0; s >>= 1) {
        if (tid < s) red[tid] = fmaxf(red[tid], red[tid+s]);
        __syncthreads();
    }
    if (tid == 0) atomicMax(&kmax_bits[bh], __float_as_uint(red[0]));
}

// ---------------------------------------------------------------------------
// Kernel B: k-hash from stored dots + kmax (same final fma as before)
// ---------------------------------------------------------------------------
__global__ __launch_bounds__(256) void khash_kernel(const float* __restrict__ pd,
                                                    const float* __restrict__ kdots,
                                                    const unsigned int* __restrict__ kmax_bits,
                                                    unsigned char* __restrict__ kh) {
    const int lin = blockIdx.x * 256 + threadIdx.x;
    const int bh = lin >> 13;
    const float4* kd = (const float4*)(kdots + (size_t)lin * 8);
    float4 d0 = kd[0], d1 = kd[1];
    float acc[NPROJ] = {d0.x, d0.y, d0.z, d0.w, d1.x, d1.y, d1.z};
    const float kn = d1.w;
    const float km = __uint_as_float(kmax_bits[bh]);
    const float ex = sqrtf(fmaxf(km*km - kn*kn, 0.f));
    int bin = 0;
    #pragma unroll
    for (int r = 0; r < NPROJ; ++r) {
        acc[r] += ex * pd[DDIM*NPROJ + r];
        bin |= (acc[r] > 0.f) << r;
    }
    kh[lin] = (unsigned char)(bin ^ (bin >> 1));
}

// ---------------------------------------------------------------------------
// Kernel C: parallel stable counting sort (128 buckets), 256 segs x 32 elems.
// ---------------------------------------------------------------------------
__global__ __launch_bounds__(256) void sort_kernel(const unsigned char* __restrict__ qhash,
                                                   const unsigned char* __restrict__ khash,
                                                   int* __restrict__ qidx,
                                                   int* __restrict__ kidx) {
    __shared__ unsigned char hsh[NSEQ];
    __shared__ unsigned short cnt[128][264];   // pitch 264 u16 = 528 B (16-aligned)
    __shared__ int base[128];
    __shared__ int wtot[2];
    const int bh = blockIdx.x, tid = threadIdx.x;
    const unsigned char* hash = blockIdx.y ? khash : qhash;
    int* idx = blockIdx.y ? kidx : qidx;

    {
        const uint4* src = (const uint4*)(hash + (size_t)bh * NSEQ);
        uint4* hdst = (uint4*)hsh;
        hdst[tid] = src[tid];
        hdst[tid + 256] = src[tid + 256];
        unsigned int* cz = (unsigned int*)&cnt[0][0];
        for (int i = tid; i < 128*264/2; i += 256) cz[i] = 0;
    }
    __syncthreads();
    {
        const unsigned char* s = hsh + tid*32;
        for (int i = 0; i < 32; ++i) cnt[s[i]][tid]++;
    }
    __syncthreads();

    int sc = 0, vv = 0;
    if (tid < 128) {
        unsigned run = 0;
        uint4* rp = (uint4*)cnt[tid];
        for (int wd = 0; wd < 32; ++wd) {
            uint4 x = rp[wd];
            unsigned v0 = x.x & 0xffffu, v1 = x.x >> 16;
            unsigned v2 = x.y & 0xffffu, v3 = x.y >> 16;
            unsigned v4 = x.z & 0xffffu, v5 = x.z >> 16;
            unsigned v6 = x.w & 0xffffu, v7 = x.w >> 16;
            unsigned p0 = run, p1 = p0+v0, p2 = p1+v1, p3 = p2+v2,
                     p4 = p3+v3, p5 = p4+v4, p6 = p5+v5, p7 = p6+v6;
            run = p7 + v7;
            x.x = p0 | (p1<<16); x.y = p2 | (p3<<16);
            x.z = p4 | (p5<<16); x.w = p6 | (p7<<16);
            rp[wd] = x;
        }
        vv = (int)run;
        sc = vv;
        #pragma unroll
        for (int d = 1; d < 64; d <<= 1) {
            int t = __shfl_up(sc, d, 64);
            if ((tid & 63) >= d) sc += t;
        }
        if ((tid & 63) == 63) wtot[tid >> 6] = sc;
    }
    __syncthreads();
    if (tid < 128) base[tid] = (sc - vv) + (tid >= 64 ? wtot[0] : 0);
    __syncthreads();
    {
        int* dst = idx + (size_t)bh * NSEQ;
        const unsigned char* s = hsh + tid*32;
        for (int i = 0; i < 32; ++i) {
            int h = s[i];
            int c = cnt[h][tid];
            cnt[h][tid] = (unsigned short)(c + 1);
            dst[base[h] + c] = tid*32 + i;
        }
    }
}

// ---------------------------------------------------------------------------
// Kernel D: MFMA fused attention.
//   out = (Sum_blk e*v + 32*Sum_res e*v) / (l_blk + 32*l_res)
// Q pre-scaled by log2(e)/8 so e = exp2(c [+5 residual bias]).
// ---------------------------------------------------------------------------

#define PPITCH 80      // bytes per q-row in P buffer (16-aligned)
#define VSWZ(d) ((((d) >> 1) & 7) << 4)

template<int PHASE>   // 0 = block-diagonal, 1 = residual
__device__ __forceinline__ void chunk_compute(
    int lane, char* Pw, int ch,
    const bf16x8 (&qhf)[4][2], const bf16x8 (&qlf)[4][2],
    f32x4 (&O)[4][4], float (&lacc)[4],
    const float* maskF, const char* KhL, const char* VthL, const char* VtlL) {

    const int lr4 = lane >> 4;
    const int lc  = lane & 15;

    #pragma unroll
    for (int half = 0; half < 2; ++half) {
        // ---- QK^T for this half's 32 keys (mt = 2*half, 2*half+1) ----
        #pragma unroll
        for (int m2 = 0; m2 < 2; ++m2) {
            const int mt = half*2 + m2;
            const int key = mt*16 + lc;
            const int ksw = (key & 7) << 4;
            bf16x8 ka0 = *(const bf16x8*)(KhL + ((key*128 +  0 + lr4*16) ^ ksw));
            bf16x8 ka1 = *(const bf16x8*)(KhL + ((key*128 + 64 + lr4*16) ^ ksw));
            float4 mk;
            if (PHASE) mk = *(const float4*)(maskF + ch*64 + mt*16 + lr4*4);
            #pragma unroll
            for (int qt = 0; qt < 4; ++qt) {
                f32x4 c = {0.f, 0.f, 0.f, 0.f};
                c = __builtin_amdgcn_mfma_f32_16x16x32_bf16(ka0, qhf[qt][0], c, 0, 0, 0);
                c = __builtin_amdgcn_mfma_f32_16x16x32_bf16(ka0, qlf[qt][0], c, 0, 0, 0);
                c = __builtin_amdgcn_mfma_f32_16x16x32_bf16(ka1, qhf[qt][1], c, 0, 0, 0);
                c = __builtin_amdgcn_mfma_f32_16x16x32_bf16(ka1, qlf[qt][1], c, 0, 0, 0);
                float e0, e1, e2, e3;
                if (PHASE) {
                    e0 = exp2f(c[0] + 5.0f) * mk.x;   // +log2(32)
                    e1 = exp2f(c[1] + 5.0f) * mk.y;
                    e2 = exp2f(c[2] + 5.0f) * mk.z;
                    e3 = exp2f(c[3] + 5.0f) * mk.w;
                } else {
                    e0 = exp2f(c[0]); e1 = exp2f(c[1]);
                    e2 = exp2f(c[2]); e3 = exp2f(c[3]);
                }
                lacc[qt] += (e0+e1) + (e2+e3);
                uint2 wv;
                wv.x = pk2bf(e0, e1);
                wv.y = pk2bf(e2, e3);
                const int qq = qt*16 + lc;
                *(uint2*)(Pw + qq*PPITCH + m2*32 + lr4*8) = wv;
            }
        }

        // ---- PV for this half's 32 keys ----
        bf16x8 pf[4];
        #pragma unroll
        for (int qt = 0; qt < 4; ++qt)
            pf[qt] = *(const bf16x8*)(Pw + (qt*16 + lc)*PPITCH + lr4*16);

        __builtin_amdgcn_s_setprio(1);
        #pragma unroll
        for (int dt = 0; dt < 4; ++dt) {
            const int d = dt*16 + lc;
            const int a = (d*128 + half*64 + lr4*16) ^ VSWZ(d);
            bf16x8 vh = *(const bf16x8*)(VthL + a);
            bf16x8 vl = *(const bf16x8*)(VtlL + a);
            #pragma unroll
            for (int qt = 0; qt < 4; ++qt) {
                O[qt][dt] = __builtin_amdgcn_mfma_f32_16x16x32_bf16(pf[qt], vh, O[qt][dt], 0, 0, 0);
                O[qt][dt] = __builtin_amdgcn_mfma_f32_16x16x32_bf16(pf[qt], vl, O[qt][dt], 0, 0, 0);
            }
        }
        __builtin_amdgcn_s_setprio(0);
    }
}

__global__ __launch_bounds__(256, 3) void attn_kernel(const float* __restrict__ q,
                                                      const float* __restrict__ k,
                                                      const float* __restrict__ v,
                                                      const int* __restrict__ samp,
                                                      const int* __restrict__ qidx,
                                                      const int* __restrict__ kidx,
                                                      float* __restrict__ out) {
    __shared__ __align__(16) char KhL[8192];
    __shared__ __align__(16) char VthL[8192];
    __shared__ __align__(16) char VtlL[8192];
    __shared__ __align__(16) char PL[4][PPITCH*64];
    __shared__ int qidxL[256];
    __shared__ int kidxL[256];
    __shared__ int ridxL[256];
    __shared__ float maskF[256];

    const int g = blockIdx.x, bh = blockIdx.y;
    const int tid = threadIdx.x;
    const int lane = tid & 63, w = tid >> 6;
    const int lr4 = lane >> 4, lc = lane & 15;
    const size_t basef = (size_t)bh * NSEQ * DDIM;

    qidxL[tid] = qidx[bh*NSEQ + g*KBLK + tid];
    kidxL[tid] = kidx[bh*NSEQ + g*KBLK + tid];
    {
        int sp = samp[bh*NSAMP + tid];
        ridxL[tid] = kidx[bh*NSEQ + sp];
        maskF[tid] = ((sp >> 8) == g) ? 0.f : 1.f;
    }
    __syncthreads();

    // Q fragments (hi/lo), pre-scaled by log2(e)/8
    bf16x8 qhf[4][2], qlf[4][2];
    #pragma unroll
    for (int qt = 0; qt < 4; ++qt) {
        const int qrow = qidxL[w*64 + qt*16 + lc];
        const float* qp = q + basef + (size_t)qrow*DDIM;
        #pragma unroll
        for (int ks = 0; ks < 2; ++ks) {
            const float* p = qp + ks*32 + lr4*8;
            float4 a = *(const float4*)p;
            float4 b = *(const float4*)(p + 4);
            float xs[8] = {a.x,a.y,a.z,a.w,b.x,b.y,b.z,b.w};
            union { bf16x8 v; unsigned int u[4]; } hv, lv;
            #pragma unroll
            for (int j = 0; j < 4; ++j) {
                float s0 = xs[2*j]   * LOG2E_8;
                float s1 = xs[2*j+1] * LOG2E_8;
                unsigned hp = pk2bf(s0, s1);
                hv.u[j] = hp;
                float l0 = s0 - __uint_as_float(hp << 16);
                float l1 = s1 - __uint_as_float(hp & 0xffff0000u);
                lv.u[j] = pk2bf(l0, l1);
            }
            qhf[qt][ks] = hv.v; qlf[qt][ks] = lv.v;
        }
    }

    f32x4 O[4][4];
    #pragma unroll
    for (int a = 0; a < 4; ++a)
        #pragma unroll
        for (int b = 0; b < 4; ++b) O[a][b] = (f32x4){0.f,0.f,0.f,0.f};
    float lacc[4] = {0,0,0,0};
    char* Pw = PL[w];

    #pragma unroll
    for (int ph = 0; ph < 2; ++ph) {
        const int* IDX = ph ? ridxL : kidxL;
        for (int ch = 0; ch < 4; ++ch) {
            __syncthreads();
            // ---- K stage: thread (kk, dc) -> 16 dims of one key ----
            {
                const int kk = tid & 63, dc = tid >> 6;
                const int korig = IDX[ch*64 + kk];
                const float* kr = k + basef + (size_t)korig*DDIM + dc*16;
                float4 f0 = ((const float4*)kr)[0], f1 = ((const float4*)kr)[1];
                float4 f2 = ((const float4*)kr)[2], f3 = ((const float4*)kr)[3];
                union { bf16x8 v; unsigned int u[4]; } h0, h1;
                h0.u[0] = pk2bf(f0.x,f0.y); h0.u[1] = pk2bf(f0.z,f0.w);
                h0.u[2] = pk2bf(f1.x,f1.y); h0.u[3] = pk2bf(f1.z,f1.w);
                h1.u[0] = pk2bf(f2.x,f2.y); h1.u[1] = pk2bf(f2.z,f2.w);
                h1.u[2] = pk2bf(f3.x,f3.y); h1.u[3] = pk2bf(f3.z,f3.w);
                const int rb = kk*128 + dc*32, sw = (kk & 7) << 4;
                *(bf16x8*)(KhL + ((rb) ^ sw)) = h0.v;
                *(bf16x8*)(KhL + ((rb + 16) ^ sw)) = h1.v;
            }
            // ---- V stage: thread (vg, kq): 4x4 register transpose, hi+lo ----
            {
                const int vg = tid & 15, kq = tid >> 4;
                const int r0 = IDX[ch*64 + kq*4 + 0];
                const int r1 = IDX[ch*64 + kq*4 + 1];
                const int r2 = IDX[ch*64 + kq*4 + 2];
                const int r3 = IDX[ch*64 + kq*4 + 3];
                float4 x0 = *(const float4*)(v + basef + (size_t)r0*DDIM + vg*4);
                float4 x1 = *(const float4*)(v + basef + (size_t)r1*DDIM + vg*4);
                float4 x2 = *(const float4*)(v + basef + (size_t)r2*DDIM + vg*4);
                float4 x3 = *(const float4*)(v + basef + (size_t)r3*DDIM + vg*4);
                const float c0[4] = {x0.x, x0.y, x0.z, x0.w};
                const float c1[4] = {x1.x, x1.y, x1.z, x1.w};
                const float c2[4] = {x2.x, x2.y, x2.z, x2.w};
                const float c3[4] = {x3.x, x3.y, x3.z, x3.w};
                #pragma unroll
                for (int j = 0; j < 4; ++j) {
                    const int d = vg*4 + j;
                    float a0 = c0[j], a1 = c1[j], a2 = c2[j], a3 = c3[j];
                    unsigned h01 = pk2bf(a0, a1), h23 = pk2bf(a2, a3);
                    float l0 = a0 - __uint_as_float(h01 << 16);
                    float l1 = a1 - __uint_as_float(h01 & 0xffff0000u);
                    float l2 = a2 - __uint_as_float(h23 << 16);
                    float l3 = a3 - __uint_as_float(h23 & 0xffff0000u);
                    unsigned w01 = pk2bf(l0, l1), w23 = pk2bf(l2, l3);
                    const int a = (d*128 + kq*8) ^ VSWZ(d);
                    *(uint2*)(VthL + a) = make_uint2(h01, h23);
                    *(uint2*)(VtlL + a) = make_uint2(w01, w23);
                }
            }
            __syncthreads();
            if (ph == 0)
                chunk_compute<0>(lane, Pw, ch, qhf, qlf, O, lacc, maskF, KhL, VthL, VtlL);
            else
                chunk_compute<1>(lane, Pw, ch, qhf, qlf, O, lacc, maskF, KhL, VthL, VtlL);
        }
    }

    // ---- epilogue: normalize, write at original query rows ----
    #pragma unroll
    for (int qt = 0; qt < 4; ++qt) {
        lacc[qt] += __shfl_xor(lacc[qt], 16, 64);
        lacc[qt] += __shfl_xor(lacc[qt], 32, 64);
        lacc[qt] = 1.f / lacc[qt];
    }
    float* ob = out + basef;
    #pragma unroll
    for (int qt = 0; qt < 4; ++qt) {
        #pragma unroll
        for (int r = 0; r < 4; ++r) {
            const float f = __shfl(lacc[qt], (lane & 48) | (lr4*4 + r), 64);
            const int orow = qidxL[w*64 + qt*16 + lr4*4 + r];
            float* p = ob + (size_t)orow*DDIM + lc;
            #pragma unroll
            for (int dt = 0; dt < 4; ++dt) p[dt*16] = O[qt][dt][r] * f;
        }
    }
}

// ---------------------------------------------------------------------------
extern "C" void kernel_launch(void* const* d_in, const int* in_sizes, int n_in,
                              void* d_out, int out_size, void* d_ws, size_t ws_size,
                              hipStream_t stream) {
    const float* q    = (const float*)d_in[0];
    const float* k    = (const float*)d_in[1];
    const float* v    = (const float*)d_in[2];
    const float* pd   = (const float*)d_in[3];
    const int*   samp = (const int*)d_in[4];
    float* out = (float*)d_out;

    char* ws = (char*)d_ws;
    // kdots occupies [0, 8 MB); qidx/kidx reuse that region after khash is done.
    float*         kdots = (float*)(ws + 0);
    int*           qidx  = (int*)(ws + 0);
    int*           kidx  = (int*)(ws + 1048576);
    unsigned char* qh    = (unsigned char*)(ws + 8388608);
    unsigned char* kh    = (unsigned char*)(ws + 8650752);
    unsigned int*  kmaxb = (unsigned int*)(ws + 8912896);

    hipMemsetAsync(kmaxb, 0, NBH*sizeof(unsigned int), stream);
    hipLaunchKernelGGL(prelude_kernel, dim3(NBH*NSEQ/256), dim3(256), 0, stream,
                       q, k, pd, kdots, kmaxb, qh);
    hipLaunchKernelGGL(khash_kernel, dim3(NBH*NSEQ/256), dim3(256), 0, stream,
                       pd, kdots, kmaxb, kh);
    hipLaunchKernelGGL(sort_kernel, dim3(NBH, 2), dim3(256), 0, stream, qh, kh, qidx, kidx);
    hipLaunchKernelGGL(attn_kernel, dim3(NB, NBH), dim3(256), 0, stream,
                       q, k, v, samp, qidx, kidx, out);
}

// Round 5
// 187.037 us; speedup vs baseline: 1.9577x; 1.9577x over previous
//
#include <hip/hip_runtime.h>
#include <hip/hip_bf16.h>
#include <math.h>

#define BD 2
#define HD 16
#define NSEQ 8192
#define DDIM 64
#define NPROJ 7
#define KBLK 256
#define NSAMP 256
#define NBH (BD*HD)           // 32
#define NB (NSEQ/KBLK)        // 32

#define LOG2E_8 0.18033688011112042f   // log2(e)/8

typedef short bf16x8 __attribute__((ext_vector_type(8)));
typedef float f32x4 __attribute__((ext_vector_type(4)));

// pack two f32 -> u32 of 2 bf16 (RTNE via v_cvt_pk_bf16_f32)
__device__ __forceinline__ unsigned int pk2bf(float a, float b) {
    union { __hip_bfloat162 h; unsigned int u; } t;
    t.h = __float22bfloat162_rn(make_float2(a, b));
    return t.u;
}

// ---------------------------------------------------------------------------
// Kernel A (fused prelude): q-hash + k-dots + k-norm + per-bh max-norm.
// Dot/norm accumulation expressions kept IDENTICAL to the passing kernel
// (hash sign bits are exact-match-critical).
// ---------------------------------------------------------------------------
__global__ __launch_bounds__(256) void prelude_kernel(const float* __restrict__ q,
                                                      const float* __restrict__ k,
                                                      const float* __restrict__ pd,
                                                      float* __restrict__ kdots,
                                                      unsigned int* __restrict__ kmax_bits,
                                                      unsigned char* __restrict__ qh) {
    __shared__ float pds[(DDIM+1)*NPROJ];
    __shared__ float red[256];
    const int tid = threadIdx.x;
    for (int i = tid; i < (DDIM+1)*NPROJ; i += 256) pds[i] = pd[i];
    __syncthreads();

    const int lin = blockIdx.x * 256 + tid;
    const int bh = lin >> 13;

    float acc[NPROJ];
    float4 xv[16];

    // ---- query hash (identical code path to passing version) ----
    {
        const float4* xp = (const float4*)(q + (size_t)lin * DDIM);
        #pragma unroll
        for (int j = 0; j < 16; ++j) xv[j] = xp[j];
        #pragma unroll
        for (int r = 0; r < NPROJ; ++r) acc[r] = 0.f;
        #pragma unroll
        for (int j = 0; j < 16; ++j) {
            float xs[4] = {xv[j].x, xv[j].y, xv[j].z, xv[j].w};
            #pragma unroll
            for (int c = 0; c < 4; ++c) {
                const int d = j*4 + c;
                #pragma unroll
                for (int r = 0; r < NPROJ; ++r) acc[r] += xs[c] * pds[d*NPROJ + r];
            }
        }
        int bin = 0;
        #pragma unroll
        for (int r = 0; r < NPROJ; ++r) bin |= (acc[r] > 0.f) << r;
        qh[lin] = (unsigned char)(bin ^ (bin >> 1));
    }

    // ---- key dots + norm ----
    float nr;
    {
        const float4* xp = (const float4*)(k + (size_t)lin * DDIM);
        #pragma unroll
        for (int j = 0; j < 16; ++j) xv[j] = xp[j];
        #pragma unroll
        for (int r = 0; r < NPROJ; ++r) acc[r] = 0.f;
        #pragma unroll
        for (int j = 0; j < 16; ++j) {
            float xs[4] = {xv[j].x, xv[j].y, xv[j].z, xv[j].w};
            #pragma unroll
            for (int c = 0; c < 4; ++c) {
                const int d = j*4 + c;
                #pragma unroll
                for (int r = 0; r < NPROJ; ++r) acc[r] += xs[c] * pds[d*NPROJ + r];
            }
        }
        float ss = 0.f;
        #pragma unroll
        for (int j = 0; j < 16; ++j) {
            float4 t = xv[j];
            ss += t.x*t.x + t.y*t.y + t.z*t.z + t.w*t.w;
        }
        nr = sqrtf(ss);
        float4* kd = (float4*)(kdots + (size_t)lin * 8);
        kd[0] = make_float4(acc[0], acc[1], acc[2], acc[3]);
        kd[1] = make_float4(acc[4], acc[5], acc[6], nr);
    }

    red[tid] = nr;
    __syncthreads();
    for (int s = 128; s > 0; s >>= 1) {
        if (tid < s) red[tid] = fmaxf(red[tid], red[tid+s]);
        __syncthreads();
    }
    if (tid == 0) atomicMax(&kmax_bits[bh], __float_as_uint(red[0]));
}

// ---------------------------------------------------------------------------
// Kernel B: k-hash from stored dots + kmax (same final fma as before)
// ---------------------------------------------------------------------------
__global__ __launch_bounds__(256) void khash_kernel(const float* __restrict__ pd,
                                                    const float* __restrict__ kdots,
                                                    const unsigned int* __restrict__ kmax_bits,
                                                    unsigned char* __restrict__ kh) {
    const int lin = blockIdx.x * 256 + threadIdx.x;
    const int bh = lin >> 13;
    const float4* kd = (const float4*)(kdots + (size_t)lin * 8);
    float4 d0 = kd[0], d1 = kd[1];
    float acc[NPROJ] = {d0.x, d0.y, d0.z, d0.w, d1.x, d1.y, d1.z};
    const float kn = d1.w;
    const float km = __uint_as_float(kmax_bits[bh]);
    const float ex = sqrtf(fmaxf(km*km - kn*kn, 0.f));
    int bin = 0;
    #pragma unroll
    for (int r = 0; r < NPROJ; ++r) {
        acc[r] += ex * pd[DDIM*NPROJ + r];
        bin |= (acc[r] > 0.f) << r;
    }
    kh[lin] = (unsigned char)(bin ^ (bin >> 1));
}

// ---------------------------------------------------------------------------
// Kernel C: parallel stable counting sort (128 buckets), 256 segs x 32 elems.
// ---------------------------------------------------------------------------
__global__ __launch_bounds__(256) void sort_kernel(const unsigned char* __restrict__ qhash,
                                                   const unsigned char* __restrict__ khash,
                                                   int* __restrict__ qidx,
                                                   int* __restrict__ kidx) {
    __shared__ unsigned char hsh[NSEQ];
    __shared__ unsigned short cnt[128][264];   // pitch 264 u16 = 528 B (16-aligned)
    __shared__ int base[128];
    __shared__ int wtot[2];
    const int bh = blockIdx.x, tid = threadIdx.x;
    const unsigned char* hash = blockIdx.y ? khash : qhash;
    int* idx = blockIdx.y ? kidx : qidx;

    {
        const uint4* src = (const uint4*)(hash + (size_t)bh * NSEQ);
        uint4* hdst = (uint4*)hsh;
        hdst[tid] = src[tid];
        hdst[tid + 256] = src[tid + 256];
        unsigned int* cz = (unsigned int*)&cnt[0][0];
        for (int i = tid; i < 128*264/2; i += 256) cz[i] = 0;
    }
    __syncthreads();
    {
        const unsigned char* s = hsh + tid*32;
        for (int i = 0; i < 32; ++i) cnt[s[i]][tid]++;
    }
    __syncthreads();

    int sc = 0, vv = 0;
    if (tid < 128) {
        unsigned run = 0;
        uint4* rp = (uint4*)cnt[tid];
        for (int wd = 0; wd < 32; ++wd) {
            uint4 x = rp[wd];
            unsigned v0 = x.x & 0xffffu, v1 = x.x >> 16;
            unsigned v2 = x.y & 0xffffu, v3 = x.y >> 16;
            unsigned v4 = x.z & 0xffffu, v5 = x.z >> 16;
            unsigned v6 = x.w & 0xffffu, v7 = x.w >> 16;
            unsigned p0 = run, p1 = p0+v0, p2 = p1+v1, p3 = p2+v2,
                     p4 = p3+v3, p5 = p4+v4, p6 = p5+v5, p7 = p6+v6;
            run = p7 + v7;
            x.x = p0 | (p1<<16); x.y = p2 | (p3<<16);
            x.z = p4 | (p5<<16); x.w = p6 | (p7<<16);
            rp[wd] = x;
        }
        vv = (int)run;
        sc = vv;
        #pragma unroll
        for (int d = 1; d < 64; d <<= 1) {
            int t = __shfl_up(sc, d, 64);
            if ((tid & 63) >= d) sc += t;
        }
        if ((tid & 63) == 63) wtot[tid >> 6] = sc;
    }
    __syncthreads();
    if (tid < 128) base[tid] = (sc - vv) + (tid >= 64 ? wtot[0] : 0);
    __syncthreads();
    {
        int* dst = idx + (size_t)bh * NSEQ;
        const unsigned char* s = hsh + tid*32;
        for (int i = 0; i < 32; ++i) {
            int h = s[i];
            int c = cnt[h][tid];
            cnt[h][tid] = (unsigned short)(c + 1);
            dst[base[h] + c] = tid*32 + i;
        }
    }
}

// ---------------------------------------------------------------------------
// Kernel D: MFMA fused attention.
//   out = (Sum_blk e*v + 32*Sum_res e*v) / (l_blk + 32*l_res)
// Q pre-scaled by log2(e)/8 so e = exp2(c [+5 residual bias]).
// launch_bounds (256,2): (256,3) round-4 A/B showed VGPR 84 + scratch spill.
// ---------------------------------------------------------------------------

#define PPITCH 80      // bytes per q-row in P buffer (16-aligned)
#define VSWZ(d) ((((d) >> 1) & 7) << 4)

template<int PHASE>   // 0 = block-diagonal, 1 = residual
__device__ __forceinline__ void chunk_compute(
    int lane, char* Pw, int ch,
    const bf16x8 (&qhf)[4][2], const bf16x8 (&qlf)[4][2],
    f32x4 (&O)[4][4], float (&lacc)[4],
    const float* maskF, const char* KhL, const char* VthL, const char* VtlL) {

    const int lr4 = lane >> 4;
    const int lc  = lane & 15;

    #pragma unroll
    for (int half = 0; half < 2; ++half) {
        // ---- QK^T for this half's 32 keys (mt = 2*half, 2*half+1) ----
        #pragma unroll
        for (int m2 = 0; m2 < 2; ++m2) {
            const int mt = half*2 + m2;
            const int key = mt*16 + lc;
            const int ksw = (key & 7) << 4;
            bf16x8 ka0 = *(const bf16x8*)(KhL + ((key*128 +  0 + lr4*16) ^ ksw));
            bf16x8 ka1 = *(const bf16x8*)(KhL + ((key*128 + 64 + lr4*16) ^ ksw));
            float4 mk;
            if (PHASE) mk = *(const float4*)(maskF + ch*64 + mt*16 + lr4*4);
            #pragma unroll
            for (int qt = 0; qt < 4; ++qt) {
                f32x4 c = {0.f, 0.f, 0.f, 0.f};
                c = __builtin_amdgcn_mfma_f32_16x16x32_bf16(ka0, qhf[qt][0], c, 0, 0, 0);
                c = __builtin_amdgcn_mfma_f32_16x16x32_bf16(ka0, qlf[qt][0], c, 0, 0, 0);
                c = __builtin_amdgcn_mfma_f32_16x16x32_bf16(ka1, qhf[qt][1], c, 0, 0, 0);
                c = __builtin_amdgcn_mfma_f32_16x16x32_bf16(ka1, qlf[qt][1], c, 0, 0, 0);
                float e0, e1, e2, e3;
                if (PHASE) {
                    e0 = exp2f(c[0] + 5.0f) * mk.x;   // +log2(32)
                    e1 = exp2f(c[1] + 5.0f) * mk.y;
                    e2 = exp2f(c[2] + 5.0f) * mk.z;
                    e3 = exp2f(c[3] + 5.0f) * mk.w;
                } else {
                    e0 = exp2f(c[0]); e1 = exp2f(c[1]);
                    e2 = exp2f(c[2]); e3 = exp2f(c[3]);
                }
                lacc[qt] += (e0+e1) + (e2+e3);
                uint2 wv;
                wv.x = pk2bf(e0, e1);
                wv.y = pk2bf(e2, e3);
                const int qq = qt*16 + lc;
                *(uint2*)(Pw + qq*PPITCH + m2*32 + lr4*8) = wv;
            }
        }

        // ---- PV for this half's 32 keys ----
        bf16x8 pf[4];
        #pragma unroll
        for (int qt = 0; qt < 4; ++qt)
            pf[qt] = *(const bf16x8*)(Pw + (qt*16 + lc)*PPITCH + lr4*16);

        __builtin_amdgcn_s_setprio(1);
        #pragma unroll
        for (int dt = 0; dt < 4; ++dt) {
            const int d = dt*16 + lc;
            const int a = (d*128 + half*64 + lr4*16) ^ VSWZ(d);
            bf16x8 vh = *(const bf16x8*)(VthL + a);
            bf16x8 vl = *(const bf16x8*)(VtlL + a);
            #pragma unroll
            for (int qt = 0; qt < 4; ++qt) {
                O[qt][dt] = __builtin_amdgcn_mfma_f32_16x16x32_bf16(pf[qt], vh, O[qt][dt], 0, 0, 0);
                O[qt][dt] = __builtin_amdgcn_mfma_f32_16x16x32_bf16(pf[qt], vl, O[qt][dt], 0, 0, 0);
            }
        }
        __builtin_amdgcn_s_setprio(0);
    }
}

__global__ __launch_bounds__(256, 2) void attn_kernel(const float* __restrict__ q,
                                                      const float* __restrict__ k,
                                                      const float* __restrict__ v,
                                                      const int* __restrict__ samp,
                                                      const int* __restrict__ qidx,
                                                      const int* __restrict__ kidx,
                                                      float* __restrict__ out) {
    __shared__ __align__(16) char KhL[8192];
    __shared__ __align__(16) char VthL[8192];
    __shared__ __align__(16) char VtlL[8192];
    __shared__ __align__(16) char PL[4][PPITCH*64];
    __shared__ int qidxL[256];
    __shared__ int kidxL[256];
    __shared__ int ridxL[256];
    __shared__ float maskF[256];

    const int g = blockIdx.x, bh = blockIdx.y;
    const int tid = threadIdx.x;
    const int lane = tid & 63, w = tid >> 6;
    const int lr4 = lane >> 4, lc = lane & 15;
    const size_t basef = (size_t)bh * NSEQ * DDIM;

    qidxL[tid] = qidx[bh*NSEQ + g*KBLK + tid];
    kidxL[tid] = kidx[bh*NSEQ + g*KBLK + tid];
    {
        int sp = samp[bh*NSAMP + tid];
        ridxL[tid] = kidx[bh*NSEQ + sp];
        maskF[tid] = ((sp >> 8) == g) ? 0.f : 1.f;
    }
    __syncthreads();

    // Q fragments (hi/lo), pre-scaled by log2(e)/8
    bf16x8 qhf[4][2], qlf[4][2];
    #pragma unroll
    for (int qt = 0; qt < 4; ++qt) {
        const int qrow = qidxL[w*64 + qt*16 + lc];
        const float* qp = q + basef + (size_t)qrow*DDIM;
        #pragma unroll
        for (int ks = 0; ks < 2; ++ks) {
            const float* p = qp + ks*32 + lr4*8;
            float4 a = *(const float4*)p;
            float4 b = *(const float4*)(p + 4);
            float xs[8] = {a.x,a.y,a.z,a.w,b.x,b.y,b.z,b.w};
            union { bf16x8 v; unsigned int u[4]; } hv, lv;
            #pragma unroll
            for (int j = 0; j < 4; ++j) {
                float s0 = xs[2*j]   * LOG2E_8;
                float s1 = xs[2*j+1] * LOG2E_8;
                unsigned hp = pk2bf(s0, s1);
                hv.u[j] = hp;
                float l0 = s0 - __uint_as_float(hp << 16);
                float l1 = s1 - __uint_as_float(hp & 0xffff0000u);
                lv.u[j] = pk2bf(l0, l1);
            }
            qhf[qt][ks] = hv.v; qlf[qt][ks] = lv.v;
        }
    }

    f32x4 O[4][4];
    #pragma unroll
    for (int a = 0; a < 4; ++a)
        #pragma unroll
        for (int b = 0; b < 4; ++b) O[a][b] = (f32x4){0.f,0.f,0.f,0.f};
    float lacc[4] = {0,0,0,0};
    char* Pw = PL[w];

    #pragma unroll
    for (int ph = 0; ph < 2; ++ph) {
        const int* IDX = ph ? ridxL : kidxL;
        for (int ch = 0; ch < 4; ++ch) {
            __syncthreads();
            // ---- K stage: thread (kk, dc) -> 16 dims of one key ----
            {
                const int kk = tid & 63, dc = tid >> 6;
                const int korig = IDX[ch*64 + kk];
                const float* kr = k + basef + (size_t)korig*DDIM + dc*16;
                float4 f0 = ((const float4*)kr)[0], f1 = ((const float4*)kr)[1];
                float4 f2 = ((const float4*)kr)[2], f3 = ((const float4*)kr)[3];
                union { bf16x8 v; unsigned int u[4]; } h0, h1;
                h0.u[0] = pk2bf(f0.x,f0.y); h0.u[1] = pk2bf(f0.z,f0.w);
                h0.u[2] = pk2bf(f1.x,f1.y); h0.u[3] = pk2bf(f1.z,f1.w);
                h1.u[0] = pk2bf(f2.x,f2.y); h1.u[1] = pk2bf(f2.z,f2.w);
                h1.u[2] = pk2bf(f3.x,f3.y); h1.u[3] = pk2bf(f3.z,f3.w);
                const int rb = kk*128 + dc*32, sw = (kk & 7) << 4;
                *(bf16x8*)(KhL + ((rb) ^ sw)) = h0.v;
                *(bf16x8*)(KhL + ((rb + 16) ^ sw)) = h1.v;
            }
            // ---- V stage: thread (vg, kq): 4x4 register transpose, hi+lo ----
            {
                const int vg = tid & 15, kq = tid >> 4;
                const int r0 = IDX[ch*64 + kq*4 + 0];
                const int r1 = IDX[ch*64 + kq*4 + 1];
                const int r2 = IDX[ch*64 + kq*4 + 2];
                const int r3 = IDX[ch*64 + kq*4 + 3];
                float4 x0 = *(const float4*)(v + basef + (size_t)r0*DDIM + vg*4);
                float4 x1 = *(const float4*)(v + basef + (size_t)r1*DDIM + vg*4);
                float4 x2 = *(const float4*)(v + basef + (size_t)r2*DDIM + vg*4);
                float4 x3 = *(const float4*)(v + basef + (size_t)r3*DDIM + vg*4);
                const float c0[4] = {x0.x, x0.y, x0.z, x0.w};
                const float c1[4] = {x1.x, x1.y, x1.z, x1.w};
                const float c2[4] = {x2.x, x2.y, x2.z, x2.w};
                const float c3[4] = {x3.x, x3.y, x3.z, x3.w};
                #pragma unroll
                for (int j = 0; j < 4; ++j) {
                    const int d = vg*4 + j;
                    float a0 = c0[j], a1 = c1[j], a2 = c2[j], a3 = c3[j];
                    unsigned h01 = pk2bf(a0, a1), h23 = pk2bf(a2, a3);
                    float l0 = a0 - __uint_as_float(h01 << 16);
                    float l1 = a1 - __uint_as_float(h01 & 0xffff0000u);
                    float l2 = a2 - __uint_as_float(h23 << 16);
                    float l3 = a3 - __uint_as_float(h23 & 0xffff0000u);
                    unsigned w01 = pk2bf(l0, l1), w23 = pk2bf(l2, l3);
                    const int a = (d*128 + kq*8) ^ VSWZ(d);
                    *(uint2*)(VthL + a) = make_uint2(h01, h23);
                    *(uint2*)(VtlL + a) = make_uint2(w01, w23);
                }
            }
            __syncthreads();
            if (ph == 0)
                chunk_compute<0>(lane, Pw, ch, qhf, qlf, O, lacc, maskF, KhL, VthL, VtlL);
            else
                chunk_compute<1>(lane, Pw, ch, qhf, qlf, O, lacc, maskF, KhL, VthL, VtlL);
        }
    }

    // ---- epilogue: normalize, write at original query rows ----
    #pragma unroll
    for (int qt = 0; qt < 4; ++qt) {
        lacc[qt] += __shfl_xor(lacc[qt], 16, 64);
        lacc[qt] += __shfl_xor(lacc[qt], 32, 64);
        lacc[qt] = 1.f / lacc[qt];
    }
    float* ob = out + basef;
    #pragma unroll
    for (int qt = 0; qt < 4; ++qt) {
        #pragma unroll
        for (int r = 0; r < 4; ++r) {
            const float f = __shfl(lacc[qt], (lane & 48) | (lr4*4 + r), 64);
            const int orow = qidxL[w*64 + qt*16 + lr4*4 + r];
            float* p = ob + (size_t)orow*DDIM + lc;
            #pragma unroll
            for (int dt = 0; dt < 4; ++dt) p[dt*16] = O[qt][dt][r] * f;
        }
    }
}

// ---------------------------------------------------------------------------
extern "C" void kernel_launch(void* const* d_in, const int* in_sizes, int n_in,
                              void* d_out, int out_size, void* d_ws, size_t ws_size,
                              hipStream_t stream) {
    const float* q    = (const float*)d_in[0];
    const float* k    = (const float*)d_in[1];
    const float* v    = (const float*)d_in[2];
    const float* pd   = (const float*)d_in[3];
    const int*   samp = (const int*)d_in[4];
    float* out = (float*)d_out;

    char* ws = (char*)d_ws;
    // kdots occupies [0, 8 MB); qidx/kidx reuse that region after khash is done.
    float*         kdots = (float*)(ws + 0);
    int*           qidx  = (int*)(ws + 0);
    int*           kidx  = (int*)(ws + 1048576);
    unsigned char* qh    = (unsigned char*)(ws + 8388608);
    unsigned char* kh    = (unsigned char*)(ws + 8650752);
    unsigned int*  kmaxb = (unsigned int*)(ws + 8912896);

    hipMemsetAsync(kmaxb, 0, NBH*sizeof(unsigned int), stream);
    hipLaunchKernelGGL(prelude_kernel, dim3(NBH*NSEQ/256), dim3(256), 0, stream,
                       q, k, pd, kdots, kmaxb, qh);
    hipLaunchKernelGGL(khash_kernel, dim3(NBH*NSEQ/256), dim3(256), 0, stream,
                       pd, kdots, kmaxb, kh);
    hipLaunchKernelGGL(sort_kernel, dim3(NBH, 2), dim3(256), 0, stream, qh, kh, qidx, kidx);
    hipLaunchKernelGGL(attn_kernel, dim3(NB, NBH), dim3(256), 0, stream,
                       q, k, v, samp, qidx, kidx, out);
}

// Round 6
// 152.348 us; speedup vs baseline: 2.4035x; 1.2277x over previous
//
#include <hip/hip_runtime.h>
#include <hip/hip_bf16.h>
#include <math.h>

#define BD 2
#define HD 16
#define NSEQ 8192
#define DDIM 64
#define NPROJ 7
#define KBLK 256
#define NSAMP 256
#define NBH (BD*HD)           // 32
#define NB (NSEQ/KBLK)        // 32

typedef short bf16x8 __attribute__((ext_vector_type(8)));
typedef float f32x4 __attribute__((ext_vector_type(4)));

// pack two f32 -> u32 of 2 bf16 (RTNE via v_cvt_pk_bf16_f32)
__device__ __forceinline__ unsigned int pk2bf(float a, float b) {
    union { __hip_bfloat162 h; unsigned int u; } t;
    t.h = __float22bfloat162_rn(make_float2(a, b));
    return t.u;
}

// ---------------------------------------------------------------------------
// Kernel A (fused prelude): q-hash + k-dots + k-norm + per-bh max-norm.
// Dot/norm accumulation kept IDENTICAL to the passing kernel (hash sign bits
// are exact-match-critical).
// ---------------------------------------------------------------------------
__global__ __launch_bounds__(256) void prelude_kernel(const float* __restrict__ q,
                                                      const float* __restrict__ k,
                                                      const float* __restrict__ pd,
                                                      float* __restrict__ kdots,
                                                      unsigned int* __restrict__ kmax_bits,
                                                      unsigned char* __restrict__ qh) {
    __shared__ float pds[(DDIM+1)*NPROJ];
    __shared__ float red[256];
    const int tid = threadIdx.x;
    for (int i = tid; i < (DDIM+1)*NPROJ; i += 256) pds[i] = pd[i];
    __syncthreads();

    const int lin = blockIdx.x * 256 + tid;
    const int bh = lin >> 13;

    float acc[NPROJ];
    float4 xv[16];

    {
        const float4* xp = (const float4*)(q + (size_t)lin * DDIM);
        #pragma unroll
        for (int j = 0; j < 16; ++j) xv[j] = xp[j];
        #pragma unroll
        for (int r = 0; r < NPROJ; ++r) acc[r] = 0.f;
        #pragma unroll
        for (int j = 0; j < 16; ++j) {
            float xs[4] = {xv[j].x, xv[j].y, xv[j].z, xv[j].w};
            #pragma unroll
            for (int c = 0; c < 4; ++c) {
                const int d = j*4 + c;
                #pragma unroll
                for (int r = 0; r < NPROJ; ++r) acc[r] += xs[c] * pds[d*NPROJ + r];
            }
        }
        int bin = 0;
        #pragma unroll
        for (int r = 0; r < NPROJ; ++r) bin |= (acc[r] > 0.f) << r;
        qh[lin] = (unsigned char)(bin ^ (bin >> 1));
    }

    float nr;
    {
        const float4* xp = (const float4*)(k + (size_t)lin * DDIM);
        #pragma unroll
        for (int j = 0; j < 16; ++j) xv[j] = xp[j];
        #pragma unroll
        for (int r = 0; r < NPROJ; ++r) acc[r] = 0.f;
        #pragma unroll
        for (int j = 0; j < 16; ++j) {
            float xs[4] = {xv[j].x, xv[j].y, xv[j].z, xv[j].w};
            #pragma unroll
            for (int c = 0; c < 4; ++c) {
                const int d = j*4 + c;
                #pragma unroll
                for (int r = 0; r < NPROJ; ++r) acc[r] += xs[c] * pds[d*NPROJ + r];
            }
        }
        float ss = 0.f;
        #pragma unroll
        for (int j = 0; j < 16; ++j) {
            float4 t = xv[j];
            ss += t.x*t.x + t.y*t.y + t.z*t.z + t.w*t.w;
        }
        nr = sqrtf(ss);
        float4* kd = (float4*)(kdots + (size_t)lin * 8);
        kd[0] = make_float4(acc[0], acc[1], acc[2], acc[3]);
        kd[1] = make_float4(acc[4], acc[5], acc[6], nr);
    }

    red[tid] = nr;
    __syncthreads();
    for (int s = 128; s > 0; s >>= 1) {
        if (tid < s) red[tid] = fmaxf(red[tid], red[tid+s]);
        __syncthreads();
    }
    if (tid == 0) atomicMax(&kmax_bits[bh], __float_as_uint(red[0]));
}

// ---------------------------------------------------------------------------
// Kernel B: k-hash from stored dots + kmax (same final fma as passing ver)
// ---------------------------------------------------------------------------
__global__ __launch_bounds__(256) void khash_kernel(const float* __restrict__ pd,
                                                    const float* __restrict__ kdots,
                                                    const unsigned int* __restrict__ kmax_bits,
                                                    unsigned char* __restrict__ kh) {
    const int lin = blockIdx.x * 256 + threadIdx.x;
    const int bh = lin >> 13;
    const float4* kd = (const float4*)(kdots + (size_t)lin * 8);
    float4 d0 = kd[0], d1 = kd[1];
    float acc[NPROJ] = {d0.x, d0.y, d0.z, d0.w, d1.x, d1.y, d1.z};
    const float kn = d1.w;
    const float km = __uint_as_float(kmax_bits[bh]);
    const float ex = sqrtf(fmaxf(km*km - kn*kn, 0.f));
    int bin = 0;
    #pragma unroll
    for (int r = 0; r < NPROJ; ++r) {
        acc[r] += ex * pd[DDIM*NPROJ + r];
        bin |= (acc[r] > 0.f) << r;
    }
    kh[lin] = (unsigned char)(bin ^ (bin >> 1));
}

// ---------------------------------------------------------------------------
// Kernel C: parallel stable counting sort (128 buckets), 256 segs x 32 elems.
// ---------------------------------------------------------------------------
__global__ __launch_bounds__(256) void sort_kernel(const unsigned char* __restrict__ qhash,
                                                   const unsigned char* __restrict__ khash,
                                                   int* __restrict__ qidx,
                                                   int* __restrict__ kidx) {
    __shared__ unsigned char hsh[NSEQ];
    __shared__ unsigned short cnt[128][264];
    __shared__ int base[128];
    __shared__ int wtot[2];
    const int bh = blockIdx.x, tid = threadIdx.x;
    const unsigned char* hash = blockIdx.y ? khash : qhash;
    int* idx = blockIdx.y ? kidx : qidx;

    {
        const uint4* src = (const uint4*)(hash + (size_t)bh * NSEQ);
        uint4* hdst = (uint4*)hsh;
        hdst[tid] = src[tid];
        hdst[tid + 256] = src[tid + 256];
        unsigned int* cz = (unsigned int*)&cnt[0][0];
        for (int i = tid; i < 128*264/2; i += 256) cz[i] = 0;
    }
    __syncthreads();
    {
        const unsigned char* s = hsh + tid*32;
        for (int i = 0; i < 32; ++i) cnt[s[i]][tid]++;
    }
    __syncthreads();

    int sc = 0, vv = 0;
    if (tid < 128) {
        unsigned run = 0;
        uint4* rp = (uint4*)cnt[tid];
        for (int wd = 0; wd < 32; ++wd) {
            uint4 x = rp[wd];
            unsigned v0 = x.x & 0xffffu, v1 = x.x >> 16;
            unsigned v2 = x.y & 0xffffu, v3 = x.y >> 16;
            unsigned v4 = x.z & 0xffffu, v5 = x.z >> 16;
            unsigned v6 = x.w & 0xffffu, v7 = x.w >> 16;
            unsigned p0 = run, p1 = p0+v0, p2 = p1+v1, p3 = p2+v2,
                     p4 = p3+v3, p5 = p4+v4, p6 = p5+v5, p7 = p6+v6;
            run = p7 + v7;
            x.x = p0 | (p1<<16); x.y = p2 | (p3<<16);
            x.z = p4 | (p5<<16); x.w = p6 | (p7<<16);
            rp[wd] = x;
        }
        vv = (int)run;
        sc = vv;
        #pragma unroll
        for (int d = 1; d < 64; d <<= 1) {
            int t = __shfl_up(sc, d, 64);
            if ((tid & 63) >= d) sc += t;
        }
        if ((tid & 63) == 63) wtot[tid >> 6] = sc;
    }
    __syncthreads();
    if (tid < 128) base[tid] = (sc - vv) + (tid >= 64 ? wtot[0] : 0);
    __syncthreads();
    {
        int* dst = idx + (size_t)bh * NSEQ;
        const unsigned char* s = hsh + tid*32;
        for (int i = 0; i < 32; ++i) {
            int h = s[i];
            int c = cnt[h][tid];
            cnt[h][tid] = (unsigned short)(c + 1);
            dst[base[h] + c] = tid*32 + i;
        }
    }
}

#define VSWZ(d) ((((d) >> 1) & 7) << 4)

// ---------------------------------------------------------------------------
// Kernel C2 (respack): prebuild the residual chunks' LDS byte-images once per
// (bh, ch) instead of 32x per g inside attn. Layout matches attn's staging
// exactly (same swizzles).
// ---------------------------------------------------------------------------
__global__ __launch_bounds__(256) void respack_kernel(const float* __restrict__ k,
                                                      const float* __restrict__ v,
                                                      const int* __restrict__ samp,
                                                      const int* __restrict__ kidx,
                                                      char* __restrict__ kres,
                                                      char* __restrict__ vres) {
    const int bh = blockIdx.x, ch = blockIdx.y, tid = threadIdx.x;
    const size_t basef = (size_t)bh * NSEQ * DDIM;
    char* kimg = kres + (size_t)(bh*4 + ch) * 8192;
    char* vimg = vres + (size_t)(bh*4 + ch) * 8192;

    // K: thread (kk, dc) -> 16 dims of one sampled key
    {
        const int kk = tid & 63, dc = tid >> 6;
        const int sp = samp[bh*NSAMP + ch*64 + kk];
        const int row = kidx[bh*NSEQ + sp];
        const float* kr = k + basef + (size_t)row*DDIM + dc*16;
        float4 f0 = ((const float4*)kr)[0], f1 = ((const float4*)kr)[1];
        float4 f2 = ((const float4*)kr)[2], f3 = ((const float4*)kr)[3];
        union { bf16x8 v8; unsigned int u[4]; } h0, h1;
        h0.u[0] = pk2bf(f0.x,f0.y); h0.u[1] = pk2bf(f0.z,f0.w);
        h0.u[2] = pk2bf(f1.x,f1.y); h0.u[3] = pk2bf(f1.z,f1.w);
        h1.u[0] = pk2bf(f2.x,f2.y); h1.u[1] = pk2bf(f2.z,f2.w);
        h1.u[2] = pk2bf(f3.x,f3.y); h1.u[3] = pk2bf(f3.z,f3.w);
        const int rb = kk*128 + dc*32, sw = (kk & 7) << 4;
        *(bf16x8*)(kimg + ((rb) ^ sw)) = h0.v8;
        *(bf16x8*)(kimg + ((rb + 16) ^ sw)) = h1.v8;
    }
    // V^T: thread (vg, kq) -> 4x4 register transpose (hi only)
    {
        const int vg = tid & 15, kq = tid >> 4;
        const int r0 = kidx[bh*NSEQ + samp[bh*NSAMP + ch*64 + kq*4 + 0]];
        const int r1 = kidx[bh*NSEQ + samp[bh*NSAMP + ch*64 + kq*4 + 1]];
        const int r2 = kidx[bh*NSEQ + samp[bh*NSAMP + ch*64 + kq*4 + 2]];
        const int r3 = kidx[bh*NSEQ + samp[bh*NSAMP + ch*64 + kq*4 + 3]];
        float4 x0 = *(const float4*)(v + basef + (size_t)r0*DDIM + vg*4);
        float4 x1 = *(const float4*)(v + basef + (size_t)r1*DDIM + vg*4);
        float4 x2 = *(const float4*)(v + basef + (size_t)r2*DDIM + vg*4);
        float4 x3 = *(const float4*)(v + basef + (size_t)r3*DDIM + vg*4);
        const float c0[4] = {x0.x, x0.y, x0.z, x0.w};
        const float c1[4] = {x1.x, x1.y, x1.z, x1.w};
        const float c2[4] = {x2.x, x2.y, x2.z, x2.w};
        const float c3[4] = {x3.x, x3.y, x3.z, x3.w};
        #pragma unroll
        for (int j = 0; j < 4; ++j) {
            const int d = vg*4 + j;
            unsigned h01 = pk2bf(c0[j], c1[j]);
            unsigned h23 = pk2bf(c2[j], c3[j]);
            *(uint2*)(vimg + ((d*128 + kq*8) ^ VSWZ(d))) = make_uint2(h01, h23);
        }
    }
}

// ---------------------------------------------------------------------------
// Kernel D: MFMA fused attention.
//   out = (Sum_blk e*v + 32*Sum_res e*v) / (l_blk + 32*l_res)
// Q pre-scaled by 0.125 (exact); e = __expf(c [+ln32]). PV single bf16 split.
// launch_bounds (256,2): (256,3/4) over-constrains allocator (round-4 spill).
// ---------------------------------------------------------------------------

#define PPITCH 80      // bytes per q-row in P buffer (16-aligned)
#define LN32 3.46573590279972f

template<int PHASE>   // 0 = block-diagonal, 1 = residual
__device__ __forceinline__ void chunk_compute(
    int lane, char* Pw, int ch,
    const bf16x8 (&qhf)[4][2], const bf16x8 (&qlf)[4][2],
    f32x4 (&O)[4][4], float (&lacc)[4],
    const float* maskF, const char* KhL, const char* VthL) {

    const int lr4 = lane >> 4;
    const int lc  = lane & 15;

    #pragma unroll
    for (int half = 0; half < 2; ++half) {
        // ---- QK^T for this half's 32 keys ----
        #pragma unroll
        for (int m2 = 0; m2 < 2; ++m2) {
            const int mt = half*2 + m2;
            const int key = mt*16 + lc;
            const int ksw = (key & 7) << 4;
            bf16x8 ka0 = *(const bf16x8*)(KhL + ((key*128 +  0 + lr4*16) ^ ksw));
            bf16x8 ka1 = *(const bf16x8*)(KhL + ((key*128 + 64 + lr4*16) ^ ksw));
            float4 mk;
            if (PHASE) mk = *(const float4*)(maskF + ch*64 + mt*16 + lr4*4);
            #pragma unroll
            for (int qt = 0; qt < 4; ++qt) {
                f32x4 c = {0.f, 0.f, 0.f, 0.f};
                c = __builtin_amdgcn_mfma_f32_16x16x32_bf16(ka0, qhf[qt][0], c, 0, 0, 0);
                c = __builtin_amdgcn_mfma_f32_16x16x32_bf16(ka0, qlf[qt][0], c, 0, 0, 0);
                c = __builtin_amdgcn_mfma_f32_16x16x32_bf16(ka1, qhf[qt][1], c, 0, 0, 0);
                c = __builtin_amdgcn_mfma_f32_16x16x32_bf16(ka1, qlf[qt][1], c, 0, 0, 0);
                float e0, e1, e2, e3;
                if (PHASE) {
                    e0 = __expf(c[0] + LN32) * mk.x;
                    e1 = __expf(c[1] + LN32) * mk.y;
                    e2 = __expf(c[2] + LN32) * mk.z;
                    e3 = __expf(c[3] + LN32) * mk.w;
                } else {
                    e0 = __expf(c[0]); e1 = __expf(c[1]);
                    e2 = __expf(c[2]); e3 = __expf(c[3]);
                }
                lacc[qt] += (e0+e1) + (e2+e3);
                uint2 wv;
                wv.x = pk2bf(e0, e1);
                wv.y = pk2bf(e2, e3);
                const int qq = qt*16 + lc;
                *(uint2*)(Pw + qq*PPITCH + m2*32 + lr4*8) = wv;
            }
        }

        // ---- PV for this half's 32 keys (single bf16 split) ----
        bf16x8 pf[4];
        #pragma unroll
        for (int qt = 0; qt < 4; ++qt)
            pf[qt] = *(const bf16x8*)(Pw + (qt*16 + lc)*PPITCH + lr4*16);

        __builtin_amdgcn_s_setprio(1);
        #pragma unroll
        for (int dt = 0; dt < 4; ++dt) {
            const int d = dt*16 + lc;
            const int a = (d*128 + half*64 + lr4*16) ^ VSWZ(d);
            bf16x8 vh = *(const bf16x8*)(VthL + a);
            #pragma unroll
            for (int qt = 0; qt < 4; ++qt) {
                O[qt][dt] = __builtin_amdgcn_mfma_f32_16x16x32_bf16(pf[qt], vh, O[qt][dt], 0, 0, 0);
            }
        }
        __builtin_amdgcn_s_setprio(0);
    }
}

__global__ __launch_bounds__(256, 2) void attn_kernel(const float* __restrict__ q,
                                                      const float* __restrict__ k,
                                                      const float* __restrict__ v,
                                                      const int* __restrict__ samp,
                                                      const int* __restrict__ qidx,
                                                      const int* __restrict__ kidx,
                                                      const char* __restrict__ kres,
                                                      const char* __restrict__ vres,
                                                      float* __restrict__ out) {
    __shared__ __align__(16) char KhL[8192];
    __shared__ __align__(16) char VthL[8192];
    __shared__ __align__(16) char PL[4][PPITCH*64];
    __shared__ int qidxL[256];
    __shared__ int kidxL[256];
    __shared__ float maskF[256];

    const int g = blockIdx.x, bh = blockIdx.y;
    const int tid = threadIdx.x;
    const int lane = tid & 63, w = tid >> 6;
    const int lr4 = lane >> 4, lc = lane & 15;
    const size_t basef = (size_t)bh * NSEQ * DDIM;

    qidxL[tid] = qidx[bh*NSEQ + g*KBLK + tid];
    kidxL[tid] = kidx[bh*NSEQ + g*KBLK + tid];
    {
        int sp = samp[bh*NSAMP + tid];
        maskF[tid] = ((sp >> 8) == g) ? 0.f : 1.f;
    }
    __syncthreads();

    // Q fragments (hi/lo), pre-scaled by 0.125 (exact)
    bf16x8 qhf[4][2], qlf[4][2];
    #pragma unroll
    for (int qt = 0; qt < 4; ++qt) {
        const int qrow = qidxL[w*64 + qt*16 + lc];
        const float* qp = q + basef + (size_t)qrow*DDIM;
        #pragma unroll
        for (int ks = 0; ks < 2; ++ks) {
            const float* p = qp + ks*32 + lr4*8;
            float4 a = *(const float4*)p;
            float4 b = *(const float4*)(p + 4);
            float xs[8] = {a.x,a.y,a.z,a.w,b.x,b.y,b.z,b.w};
            union { bf16x8 v8; unsigned int u[4]; } hv, lv;
            #pragma unroll
            for (int j = 0; j < 4; ++j) {
                float s0 = xs[2*j]   * 0.125f;
                float s1 = xs[2*j+1] * 0.125f;
                unsigned hp = pk2bf(s0, s1);
                hv.u[j] = hp;
                float l0 = s0 - __uint_as_float(hp << 16);
                float l1 = s1 - __uint_as_float(hp & 0xffff0000u);
                lv.u[j] = pk2bf(l0, l1);
            }
            qhf[qt][ks] = hv.v8; qlf[qt][ks] = lv.v8;
        }
    }

    f32x4 O[4][4];
    #pragma unroll
    for (int a = 0; a < 4; ++a)
        #pragma unroll
        for (int b = 0; b < 4; ++b) O[a][b] = (f32x4){0.f,0.f,0.f,0.f};
    float lacc[4] = {0,0,0,0};
    char* Pw = PL[w];

    // ==== PHASE 0: block-diagonal (gather-staged) ====
    for (int ch = 0; ch < 4; ++ch) {
        __syncthreads();
        {
            const int kk = tid & 63, dc = tid >> 6;
            const int korig = kidxL[ch*64 + kk];
            const float* kr = k + basef + (size_t)korig*DDIM + dc*16;
            float4 f0 = ((const float4*)kr)[0], f1 = ((const float4*)kr)[1];
            float4 f2 = ((const float4*)kr)[2], f3 = ((const float4*)kr)[3];
            union { bf16x8 v8; unsigned int u[4]; } h0, h1;
            h0.u[0] = pk2bf(f0.x,f0.y); h0.u[1] = pk2bf(f0.z,f0.w);
            h0.u[2] = pk2bf(f1.x,f1.y); h0.u[3] = pk2bf(f1.z,f1.w);
            h1.u[0] = pk2bf(f2.x,f2.y); h1.u[1] = pk2bf(f2.z,f2.w);
            h1.u[2] = pk2bf(f3.x,f3.y); h1.u[3] = pk2bf(f3.z,f3.w);
            const int rb = kk*128 + dc*32, sw = (kk & 7) << 4;
            *(bf16x8*)(KhL + ((rb) ^ sw)) = h0.v8;
            *(bf16x8*)(KhL + ((rb + 16) ^ sw)) = h1.v8;
        }
        {
            const int vg = tid & 15, kq = tid >> 4;
            const int r0 = kidxL[ch*64 + kq*4 + 0];
            const int r1 = kidxL[ch*64 + kq*4 + 1];
            const int r2 = kidxL[ch*64 + kq*4 + 2];
            const int r3 = kidxL[ch*64 + kq*4 + 3];
            float4 x0 = *(const float4*)(v + basef + (size_t)r0*DDIM + vg*4);
            float4 x1 = *(const float4*)(v + basef + (size_t)r1*DDIM + vg*4);
            float4 x2 = *(const float4*)(v + basef + (size_t)r2*DDIM + vg*4);
            float4 x3 = *(const float4*)(v + basef + (size_t)r3*DDIM + vg*4);
            const float c0[4] = {x0.x, x0.y, x0.z, x0.w};
            const float c1[4] = {x1.x, x1.y, x1.z, x1.w};
            const float c2[4] = {x2.x, x2.y, x2.z, x2.w};
            const float c3[4] = {x3.x, x3.y, x3.z, x3.w};
            #pragma unroll
            for (int j = 0; j < 4; ++j) {
                const int d = vg*4 + j;
                unsigned h01 = pk2bf(c0[j], c1[j]);
                unsigned h23 = pk2bf(c2[j], c3[j]);
                *(uint2*)(VthL + ((d*128 + kq*8) ^ VSWZ(d))) = make_uint2(h01, h23);
            }
        }
        __syncthreads();
        chunk_compute<0>(lane, Pw, ch, qhf, qlf, O, lacc, maskF, KhL, VthL);
    }

    // ==== PHASE 1: residual (prepacked image copy) ====
    for (int ch = 0; ch < 4; ++ch) {
        __syncthreads();
        {
            const char* ks = kres + (size_t)(bh*4 + ch) * 8192 + tid*32;
            const char* vs = vres + (size_t)(bh*4 + ch) * 8192 + tid*32;
            float4 a0 = *(const float4*)ks;
            float4 a1 = *(const float4*)(ks + 16);
            float4 b0 = *(const float4*)vs;
            float4 b1 = *(const float4*)(vs + 16);
            *(float4*)(KhL + tid*32)       = a0;
            *(float4*)(KhL + tid*32 + 16)  = a1;
            *(float4*)(VthL + tid*32)      = b0;
            *(float4*)(VthL + tid*32 + 16) = b1;
        }
        __syncthreads();
        chunk_compute<1>(lane, Pw, ch, qhf, qlf, O, lacc, maskF, KhL, VthL);
    }

    // ---- epilogue: normalize, write at original query rows ----
    #pragma unroll
    for (int qt = 0; qt < 4; ++qt) {
        lacc[qt] += __shfl_xor(lacc[qt], 16, 64);
        lacc[qt] += __shfl_xor(lacc[qt], 32, 64);
        lacc[qt] = 1.f / lacc[qt];
    }
    float* ob = out + basef;
    #pragma unroll
    for (int qt = 0; qt < 4; ++qt) {
        #pragma unroll
        for (int r = 0; r < 4; ++r) {
            const float f = __shfl(lacc[qt], (lane & 48) | (lr4*4 + r), 64);
            const int orow = qidxL[w*64 + qt*16 + lr4*4 + r];
            float* p = ob + (size_t)orow*DDIM + lc;
            #pragma unroll
            for (int dt = 0; dt < 4; ++dt) p[dt*16] = O[qt][dt][r] * f;
        }
    }
}

// ---------------------------------------------------------------------------
extern "C" void kernel_launch(void* const* d_in, const int* in_sizes, int n_in,
                              void* d_out, int out_size, void* d_ws, size_t ws_size,
                              hipStream_t stream) {
    const float* q    = (const float*)d_in[0];
    const float* k    = (const float*)d_in[1];
    const float* v    = (const float*)d_in[2];
    const float* pd   = (const float*)d_in[3];
    const int*   samp = (const int*)d_in[4];
    float* out = (float*)d_out;

    char* ws = (char*)d_ws;
    // kdots occupies [0, 8 MB) and is dead after khash; qidx/kidx/kres/vres
    // overlay that region afterwards.
    float*         kdots = (float*)(ws + 0);
    int*           qidx  = (int*)(ws + 0);
    int*           kidx  = (int*)(ws + 1048576);
    char*          kres  = ws + 2097152;
    char*          vres  = ws + 3145728;
    unsigned char* qh    = (unsigned char*)(ws + 8388608);
    unsigned char* kh    = (unsigned char*)(ws + 8650752);
    unsigned int*  kmaxb = (unsigned int*)(ws + 8912896);

    hipMemsetAsync(kmaxb, 0, NBH*sizeof(unsigned int), stream);
    hipLaunchKernelGGL(prelude_kernel, dim3(NBH*NSEQ/256), dim3(256), 0, stream,
                       q, k, pd, kdots, kmaxb, qh);
    hipLaunchKernelGGL(khash_kernel, dim3(NBH*NSEQ/256), dim3(256), 0, stream,
                       pd, kdots, kmaxb, kh);
    hipLaunchKernelGGL(sort_kernel, dim3(NBH, 2), dim3(256), 0, stream, qh, kh, qidx, kidx);
    hipLaunchKernelGGL(respack_kernel, dim3(NBH, 4), dim3(256), 0, stream,
                       k, v, samp, kidx, kres, vres);
    hipLaunchKernelGGL(attn_kernel, dim3(NB, NBH), dim3(256), 0, stream,
                       q, k, v, samp, qidx, kidx, kres, vres, out);
}